// Round 1
// baseline (4135.662 us; speedup 1.0000x reference)
//
#include <hip/hip_runtime.h>

#define B_ 16
#define T_ 128
#define OBS_ 64
#define SLOTS_ 67
#define E_ 32
#define H_ 4
#define HD_ 8
#define FFN_ 64
#define QKP 33  // padded LDS row stride for q/k/v (33 % 32 != 0 -> conflict-free row reads)

__device__ __forceinline__ float red32(float v) {
  v += __shfl_xor(v, 16); v += __shfl_xor(v, 8); v += __shfl_xor(v, 4);
  v += __shfl_xor(v, 2);  v += __shfl_xor(v, 1);
  return v;
}
__device__ __forceinline__ float red8(float v) {
  v += __shfl_xor(v, 4); v += __shfl_xor(v, 2); v += __shfl_xor(v, 1);
  return v;
}
__device__ __forceinline__ float red64(float v) {
  v += __shfl_xor(v, 32); v += __shfl_xor(v, 16); v += __shfl_xor(v, 8);
  v += __shfl_xor(v, 4);  v += __shfl_xor(v, 2);  v += __shfl_xor(v, 1);
  return v;
}
__device__ __forceinline__ float redmax64(float v) {
  v = fmaxf(v, __shfl_xor(v, 32)); v = fmaxf(v, __shfl_xor(v, 16));
  v = fmaxf(v, __shfl_xor(v, 8));  v = fmaxf(v, __shfl_xor(v, 4));
  v = fmaxf(v, __shfl_xor(v, 2));  v = fmaxf(v, __shfl_xor(v, 1));
  return v;
}

// ---------------- embed + input rmsnorm ----------------
__global__ __launch_bounds__(256) void embed_kernel(
    const float* __restrict__ obs, const float* __restrict__ Wval,
    const float* __restrict__ bval, const float* __restrict__ innw,
    const float* __restrict__ dimemb, const float* __restrict__ cls,
    float* __restrict__ X) {
  int tok = blockIdx.x * 8 + (threadIdx.x >> 5);
  int e = threadIdx.x & 31;
  const int total = B_ * T_ * SLOTS_;
  if (tok >= total) return;
  int slot = tok % SLOTS_;
  int bt = tok / SLOTS_;
  float v;
  if (slot < OBS_) {
    float o = obs[bt * OBS_ + slot];
    v = o * Wval[e] + bval[e] + dimemb[slot * E_ + e];
  } else {
    v = cls[(slot - OBS_) * E_ + e];
  }
  float ss = red32(v * v);
  X[tok * E_ + e] = v * rsqrtf(ss * (1.0f / E_) + 1e-6f) * innw[e];
}

// ---------------- one full attention block, one workgroup per sequence ----------------
template <int S, bool TEMPORAL>
__global__ __launch_bounds__(256) void attn_block_kernel(
    float* __restrict__ X,
    const float* __restrict__ Wq, const float* __restrict__ Wk,
    const float* __restrict__ Wv, const float* __restrict__ Wo,
    const float* __restrict__ Wg, const float* __restrict__ Wvl,
    const float* __restrict__ Wout, const float* __restrict__ norm4,
    const float* __restrict__ qkn) {
  __shared__ float xs[S * E_];     // residual stream
  __shared__ float A[S * FFN_];    // h / o / ffn scratch
  __shared__ float qs[S * QKP];    // q, later ao, later h2
  __shared__ float ks[S * QKP];    // k, later ffn-out
  __shared__ float vs[S * QKP];    // v
  __shared__ float pbuf[4 * 128];  // per-wave softmax row (S <= 128)

  const int tid = threadIdx.x;
  int base, stride;
  if (TEMPORAL) {
    int b = blockIdx.x / SLOTS_;
    int slot = blockIdx.x % SLOTS_;
    base = (b * T_ * SLOTS_ + slot) * E_;
    stride = SLOTS_ * E_;
  } else {
    base = blockIdx.x * S * E_;
    stride = E_;
  }

  // load x
  for (int idx = tid; idx < S * E_; idx += 256) {
    int s = idx >> 5, e = idx & 31;
    xs[idx] = X[base + s * stride + e];
  }
  __syncthreads();

  // h = rmsnorm(x, norm4[0]) -> A[:, 0:32]
  {
    int e = tid & 31;
    float w = norm4[e];
    for (int s = tid >> 5; s < S; s += 8) {
      float v = xs[s * E_ + e];
      float ss = red32(v * v);
      A[s * FFN_ + e] = v * rsqrtf(ss * (1.0f / E_) + 1e-6f) * w;
    }
  }
  __syncthreads();

  // q/k/v projections (32x32 each)
  for (int idx = tid; idx < S * E_; idx += 256) {
    int s = idx >> 5, d = idx & 31;
    const float* wq = Wq + d * E_;
    const float* wk = Wk + d * E_;
    const float* wv = Wv + d * E_;
    const float* hrow = A + s * FFN_;
    float aq = 0.f, ak = 0.f, av = 0.f;
#pragma unroll
    for (int w = 0; w < E_; w++) {
      float hv = hrow[w];
      aq += hv * wq[w]; ak += hv * wk[w]; av += hv * wv[w];
    }
    qs[s * QKP + d] = aq; ks[s * QKP + d] = ak; vs[s * QKP + d] = av;
  }
  __syncthreads();

  // per-head rmsnorm of q,k (over HD=8) + optional RoPE
  {
    int d = tid & 31;
    int hd = d & 7;
    float qw = qkn[hd], kw = qkn[8 + hd];
    float theta = 0.f;
    if (TEMPORAL) theta = powf(10000.f, -(float)(hd & 3) * 0.25f);
    for (int idx = tid; idx < S * E_; idx += 256) {
      int s = idx >> 5;
      float qv = qs[s * QKP + d];
      float kv = ks[s * QKP + d];
      float qss = red8(qv * qv);
      float kss = red8(kv * kv);
      qv = qv * rsqrtf(qss * (1.0f / HD_) + 1e-6f) * qw;
      kv = kv * rsqrtf(kss * (1.0f / HD_) + 1e-6f) * kw;
      if (TEMPORAL) {
        float ang = (float)s * theta;
        float c = cosf(ang), sn = sinf(ang);
        float qp = __shfl_xor(qv, 4);
        float kp = __shfl_xor(kv, 4);
        qv = (hd < 4) ? (qv * c - qp * sn) : (qv * c + qp * sn);
        kv = (hd < 4) ? (kv * c - kp * sn) : (kv * c + kp * sn);
      }
      qs[s * QKP + d] = qv;
      ks[s * QKP + d] = kv;
    }
  }
  __syncthreads();

  // attention: one wave per (query, head) row; o -> A[:, 0:32]
  {
    const int wave = tid >> 6, lane = tid & 63;
    const float isq = 0.35355339059327373f;  // 1/sqrt(8)
    const int hd = lane & 7, kg = lane >> 3;
    for (int r = wave; r < S * H_; r += 4) {  // exactly S iterations per wave
      int sq = r >> 2;
      int head = r & 3;
      int off = head * HD_;
      float qreg[8];
#pragma unroll
      for (int j = 0; j < 8; j++) qreg[j] = qs[sq * QKP + off + j];
      int k1 = lane, k2 = lane + 64;
      float s1 = -1e30f, s2 = -1e30f;
      if (k1 < S) {
        float a = 0.f;
#pragma unroll
        for (int j = 0; j < 8; j++) a += qreg[j] * ks[k1 * QKP + off + j];
        s1 = a * isq;
      }
      if (k2 < S) {
        float a = 0.f;
#pragma unroll
        for (int j = 0; j < 8; j++) a += qreg[j] * ks[k2 * QKP + off + j];
        s2 = a * isq;
      }
      float m = redmax64(fmaxf(s1, s2));
      float e1 = (k1 < S) ? expf(s1 - m) : 0.f;
      float e2 = (k2 < S) ? expf(s2 - m) : 0.f;
      float inv = 1.0f / red64(e1 + e2);
      if (k1 < S) pbuf[wave * 128 + k1] = e1 * inv;
      if (k2 < S) pbuf[wave * 128 + k2] = e2 * inv;
      __syncthreads();  // uniform trip count across all waves; guards pbuf write->read
      float acc = 0.f;
      for (int k = kg; k < S; k += 8)
        acc += pbuf[wave * 128 + k] * vs[k * QKP + off + hd];
      acc += __shfl_xor(acc, 8); acc += __shfl_xor(acc, 16); acc += __shfl_xor(acc, 32);
      if (lane < 8) A[sq * FFN_ + off + lane] = acc;
    }
  }
  __syncthreads();

  // ao = o @ Wo -> qs
  for (int idx = tid; idx < S * E_; idx += 256) {
    int s = idx >> 5, d = idx & 31;
    const float* wo = Wo + d * E_;
    const float* orow = A + s * FFN_;
    float a = 0.f;
#pragma unroll
    for (int w = 0; w < E_; w++) a += orow[w] * wo[w];
    qs[s * QKP + d] = a;
  }
  __syncthreads();

  // x += rmsnorm(ao, norm4[1])
  {
    int e = tid & 31;
    float w1 = norm4[E_ + e];
    for (int s = tid >> 5; s < S; s += 8) {
      float v = qs[s * QKP + e];
      float ss = red32(v * v);
      xs[s * E_ + e] += v * rsqrtf(ss * (1.0f / E_) + 1e-6f) * w1;
    }
  }
  __syncthreads();

  // h2 = rmsnorm(x, norm4[2]) -> qs
  {
    int e = tid & 31;
    float w2 = norm4[2 * E_ + e];
    for (int s = tid >> 5; s < S; s += 8) {
      float v = xs[s * E_ + e];
      float ss = red32(v * v);
      qs[s * QKP + e] = v * rsqrtf(ss * (1.0f / E_) + 1e-6f) * w2;
    }
  }
  __syncthreads();

  // ffn = silu(h2@Wg) * (h2@Wval) -> A
  for (int idx = tid; idx < S * FFN_; idx += 256) {
    int s = idx >> 6, f = idx & 63;
    const float* wg = Wg + f * E_;
    const float* wv2 = Wvl + f * E_;
    const float* hrow = qs + s * QKP;
    float g = 0.f, vv = 0.f;
#pragma unroll
    for (int w = 0; w < E_; w++) {
      float hv = hrow[w];
      g += hv * wg[w]; vv += hv * wv2[w];
    }
    float sg = g / (1.0f + expf(-g));
    A[s * FFN_ + f] = sg * vv;
  }
  __syncthreads();

  // out = ffn @ Wout^T ('bsf,wf->bsw') -> ks
  for (int idx = tid; idx < S * E_; idx += 256) {
    int s = idx >> 5, w = idx & 31;
    const float* wo2 = Wout + w * FFN_;
    const float* frow = A + s * FFN_;
    float a = 0.f;
#pragma unroll
    for (int f = 0; f < FFN_; f++) a += frow[f] * wo2[f];
    ks[s * QKP + w] = a;
  }
  __syncthreads();

  // x += rmsnorm(out, norm4[3])
  {
    int e = tid & 31;
    float w3 = norm4[3 * E_ + e];
    for (int s = tid >> 5; s < S; s += 8) {
      float v = ks[s * QKP + e];
      float ss = red32(v * v);
      xs[s * E_ + e] += v * rsqrtf(ss * (1.0f / E_) + 1e-6f) * w3;
    }
  }
  __syncthreads();

  // store x
  for (int idx = tid; idx < S * E_; idx += 256) {
    int s = idx >> 5, e = idx & 31;
    X[base + s * stride + e] = xs[idx];
  }
}

// ---------------- final norm + output extraction ----------------
__global__ __launch_bounds__(256) void final_kernel(const float* __restrict__ X,
                                                    const float* __restrict__ fnw,
                                                    float* __restrict__ out) {
  int tok = blockIdx.x * 8 + (threadIdx.x >> 5);
  int e = threadIdx.x & 31;
  if (tok >= B_ * 3) return;
  int b = tok / 3, j = tok % 3;
  const float* xp = X + ((size_t)(b * T_ + (T_ - 1)) * SLOTS_ + OBS_ + j) * E_;
  float v = xp[e];
  float ss = red32(v * v);
  out[j * (B_ * E_) + b * E_ + e] = v * rsqrtf(ss * (1.0f / E_) + 1e-6f) * fnw[e];
}

extern "C" void kernel_launch(void* const* d_in, const int* in_sizes, int n_in,
                              void* d_out, int out_size, void* d_ws, size_t ws_size,
                              hipStream_t stream) {
  (void)in_sizes; (void)n_in; (void)out_size; (void)ws_size;
  const float* obs          = (const float*)d_in[0];
  const float* W_val        = (const float*)d_in[1];
  const float* b_val        = (const float*)d_in[2];
  const float* input_norm_w = (const float*)d_in[3];
  const float* dim_embed    = (const float*)d_in[4];
  const float* cls_tokens   = (const float*)d_in[5];
  const float* final_norm_w = (const float*)d_in[6];
  const float* s_Wq   = (const float*)d_in[7];
  const float* s_Wk   = (const float*)d_in[8];
  const float* s_Wv   = (const float*)d_in[9];
  const float* s_Wo   = (const float*)d_in[10];
  const float* s_Wg   = (const float*)d_in[11];
  const float* s_Wvl  = (const float*)d_in[12];
  const float* s_Wout = (const float*)d_in[13];
  const float* s_n4   = (const float*)d_in[14];
  const float* s_qkn  = (const float*)d_in[15];
  const float* t_Wq   = (const float*)d_in[16];
  const float* t_Wk   = (const float*)d_in[17];
  const float* t_Wv   = (const float*)d_in[18];
  const float* t_Wo   = (const float*)d_in[19];
  const float* t_Wg   = (const float*)d_in[20];
  const float* t_Wvl  = (const float*)d_in[21];
  const float* t_Wout = (const float*)d_in[22];
  const float* t_n4   = (const float*)d_in[23];
  const float* t_qkn  = (const float*)d_in[24];

  float* X = (float*)d_ws;  // B*T*SLOTS*E floats = 17.56 MB
  float* out = (float*)d_out;

  const int total_tokens = B_ * T_ * SLOTS_;
  embed_kernel<<<(total_tokens + 7) / 8, 256, 0, stream>>>(
      obs, W_val, b_val, input_norm_w, dim_embed, cls_tokens, X);

  const int MM = E_ * E_;      // 1024
  const int MF = FFN_ * E_;    // 2048
  const int N4 = 4 * E_;       // 128
  const int QN = 2 * HD_;      // 16

#define SPATIAL(i)                                                              \
  attn_block_kernel<SLOTS_, false><<<B_ * T_, 256, 0, stream>>>(                \
      X, s_Wq + (i)*MM, s_Wk + (i)*MM, s_Wv + (i)*MM, s_Wo + (i)*MM,            \
      s_Wg + (i)*MF, s_Wvl + (i)*MF, s_Wout + (i)*MF, s_n4 + (i)*N4,            \
      s_qkn + (i)*QN)
#define TEMPORAL(i)                                                             \
  attn_block_kernel<T_, true><<<B_ * SLOTS_, 256, 0, stream>>>(                 \
      X, t_Wq + (i)*MM, t_Wk + (i)*MM, t_Wv + (i)*MM, t_Wo + (i)*MM,            \
      t_Wg + (i)*MF, t_Wvl + (i)*MF, t_Wout + (i)*MF, t_n4 + (i)*N4,            \
      t_qkn + (i)*QN)

  SPATIAL(0);
  TEMPORAL(0);
  SPATIAL(1);
  TEMPORAL(1);
  SPATIAL(2);

#undef SPATIAL
#undef TEMPORAL

  final_kernel<<<6, 256, 0, stream>>>(X, final_norm_w, out);
}

// Round 2
// 2867.835 us; speedup vs baseline: 1.4421x; 1.4421x over previous
//
#include <hip/hip_runtime.h>

#define B_ 16
#define T_ 128
#define OBS_ 64
#define SLOTS_ 67
#define E_ 32
#define H_ 4
#define HD_ 8
#define FFN_ 64

__device__ __forceinline__ float red32(float v) {
  v += __shfl_xor(v, 16); v += __shfl_xor(v, 8); v += __shfl_xor(v, 4);
  v += __shfl_xor(v, 2);  v += __shfl_xor(v, 1);
  return v;
}
__device__ __forceinline__ float red8(float v) {
  v += __shfl_xor(v, 4); v += __shfl_xor(v, 2); v += __shfl_xor(v, 1);
  return v;
}
__device__ __forceinline__ float red64(float v) {
  v += __shfl_xor(v, 32); v += __shfl_xor(v, 16); v += __shfl_xor(v, 8);
  v += __shfl_xor(v, 4);  v += __shfl_xor(v, 2);  v += __shfl_xor(v, 1);
  return v;
}
__device__ __forceinline__ float redmax64(float v) {
  v = fmaxf(v, __shfl_xor(v, 32)); v = fmaxf(v, __shfl_xor(v, 16));
  v = fmaxf(v, __shfl_xor(v, 8));  v = fmaxf(v, __shfl_xor(v, 4));
  v = fmaxf(v, __shfl_xor(v, 2));  v = fmaxf(v, __shfl_xor(v, 1));
  return v;
}
__device__ __forceinline__ float dot8(float4 a, float4 b, float4 c, float4 d) {
  return a.x * c.x + a.y * c.y + a.z * c.z + a.w * c.w +
         b.x * d.x + b.y * d.y + b.z * d.z + b.w * d.w;
}

// ---------------- embed + input rmsnorm ----------------
__global__ __launch_bounds__(256) void embed_kernel(
    const float* __restrict__ obs, const float* __restrict__ Wval,
    const float* __restrict__ bval, const float* __restrict__ innw,
    const float* __restrict__ dimemb, const float* __restrict__ cls,
    float* __restrict__ X) {
  int tok = blockIdx.x * 8 + (threadIdx.x >> 5);
  int e = threadIdx.x & 31;
  const int total = B_ * T_ * SLOTS_;
  if (tok >= total) return;
  int slot = tok % SLOTS_;
  int bt = tok / SLOTS_;
  float v;
  if (slot < OBS_) {
    float o = obs[bt * OBS_ + slot];
    v = o * Wval[e] + bval[e] + dimemb[slot * E_ + e];
  } else {
    v = cls[(slot - OBS_) * E_ + e];
  }
  float ss = red32(v * v);
  X[tok * E_ + e] = v * rsqrtf(ss * (1.0f / E_) + 1e-6f) * innw[e];
}

// ---------------- one full attention block per workgroup ----------------
template <int S, bool TEMPORAL>
__global__ __launch_bounds__(256, 2) void attn_block_kernel(
    float* __restrict__ X,
    const float* __restrict__ Wq, const float* __restrict__ Wk,
    const float* __restrict__ Wv, const float* __restrict__ Wo,
    const float* __restrict__ Wg, const float* __restrict__ Wvl,
    const float* __restrict__ Wout, const float* __restrict__ norm4,
    const float* __restrict__ qkn) {
  constexpr int SREG = (S + 7) / 8;  // xs registers per thread
  constexpr int KP = 36;             // padded k/v row stride (even bank spread)
  // layout: [h S*32 | q S*32 | k S*36 | v S*36 | pbuf 1024]; ffn(S*64) overlays k+v
  __shared__ __align__(16) float smem[S * 136 + 1024];
  float* hbuf = smem;             // h, then o
  float* qbuf = smem + S * 32;    // q, then h2
  float* kbuf = smem + S * 64;    // k
  float* vbuf = smem + S * 100;   // v
  float* ffnb = smem + S * 64;    // ffn overlay (S*64 <= S*72)
  float* pbuf = smem + S * 136;   // 4 waves * 2 * 128

  const int tid = threadIdx.x;
  const int e = tid & 31;
  const int srow = tid >> 5;

  int base, stride;
  if (TEMPORAL) {
    int b = blockIdx.x / SLOTS_;
    int slot = blockIdx.x % SLOTS_;
    base = (b * T_ * SLOTS_ + slot) * E_;
    stride = SLOTS_ * E_;
  } else {
    base = blockIdx.x * S * E_;
    stride = E_;
  }

  const float nw0 = norm4[e], nw1 = norm4[E_ + e], nw2 = norm4[2 * E_ + e],
              nw3 = norm4[3 * E_ + e];

  // ---- phase 1: load x into registers, h = rmsnorm(x) -> hbuf ----
  float xr[SREG];
#pragma unroll
  for (int k = 0; k < SREG; k++) {
    int s = srow + 8 * k;
    if (S % 8 == 0 || s < S) {
      xr[k] = X[base + s * stride + e];
      float ss = red32(xr[k] * xr[k]);
      hbuf[s * 32 + e] = xr[k] * rsqrtf(ss * (1.0f / E_) + 1e-6f) * nw0;
    }
  }
  __syncthreads();

  // ---- phase 2: q/k/v projection + head rmsnorm + RoPE (regs), write LDS ----
  {
    const int d = e;                 // output dim this thread owns
    const int hd = d & 7;
    const float qw = qkn[hd], kw = qkn[8 + hd];
    float theta = 0.f;
    if (TEMPORAL) theta = exp2f(-(float)(hd & 3) * 3.3219280948873623f);
    const float4* wq4 = (const float4*)(Wq + d * E_);
    const float4* wk4 = (const float4*)(Wk + d * E_);
    const float4* wv4 = (const float4*)(Wv + d * E_);
    for (int idx = tid; idx < S * E_; idx += 256) {
      int s = idx >> 5;
      const float4* h4 = (const float4*)(hbuf + s * 32);
      float aq = 0.f, ak = 0.f, av = 0.f;
#pragma unroll
      for (int j = 0; j < 8; j++) {
        float4 hh = h4[j];
        float4 a = wq4[j], b = wk4[j], c = wv4[j];
        aq += hh.x * a.x + hh.y * a.y + hh.z * a.z + hh.w * a.w;
        ak += hh.x * b.x + hh.y * b.y + hh.z * b.z + hh.w * b.w;
        av += hh.x * c.x + hh.y * c.y + hh.z * c.z + hh.w * c.w;
      }
      float qss = red8(aq * aq);
      float kss = red8(ak * ak);
      float qv = aq * rsqrtf(qss * (1.0f / HD_) + 1e-6f) * qw;
      float kv = ak * rsqrtf(kss * (1.0f / HD_) + 1e-6f) * kw;
      if (TEMPORAL) {
        float ang = (float)s * theta;
        float c, sn;
        __sincosf(ang, &sn, &c);
        float qp = __shfl_xor(qv, 4);
        float kp = __shfl_xor(kv, 4);
        qv = (hd < 4) ? (qv * c - qp * sn) : (qv * c + qp * sn);
        kv = (hd < 4) ? (kv * c - kp * sn) : (kv * c + kp * sn);
      }
      qbuf[s * 32 + d] = qv;
      kbuf[s * KP + d] = kv;
      vbuf[s * KP + d] = av;
    }
  }
  __syncthreads();

  // ---- phase 3: attention; wave w owns head w; no barriers inside ----
  {
    const int wave = tid >> 6, lane = tid & 63;
    const int off = wave * HD_;
    const int hd = lane & 7, kg = lane >> 3;
    const float isq = 0.35355339059327373f;  // 1/sqrt(8)
    const int k1 = lane, k2 = lane + 64;
    float* pw = pbuf + wave * 256;
    for (int sq = 0; sq < S; sq++) {
      const float4* q4 = (const float4*)(qbuf + sq * 32 + off);
      float4 qa = q4[0], qb = q4[1];
      float s1, s2 = -1e30f;
      {
        const float4* kk = (const float4*)(kbuf + k1 * KP + off);
        s1 = dot8(qa, qb, kk[0], kk[1]) * isq;
      }
      if (S > 64 && (S >= 128 || k2 < S)) {
        const float4* kk = (const float4*)(kbuf + k2 * KP + off);
        s2 = dot8(qa, qb, kk[0], kk[1]) * isq;
      }
      float m = redmax64(fmaxf(s1, s2));
      float e1 = __expf(s1 - m);
      float e2 = (S > 64 && (S >= 128 || k2 < S)) ? __expf(s2 - m) : 0.f;
      float inv = 1.0f / red64(e1 + e2);
      float* pb = pw + (sq & 1) * 128;
      pb[k1] = e1 * inv;
      if (S > 64 && (S >= 128 || k2 < S)) pb[k2] = e2 * inv;
      float acc = 0.f;
#pragma unroll (S >= 128 ? 16 : 4)
      for (int k = kg; k < S; k += 8)
        acc += pb[k] * vbuf[k * KP + off + hd];
      acc += __shfl_xor(acc, 8); acc += __shfl_xor(acc, 16); acc += __shfl_xor(acc, 32);
      if (lane < 8) hbuf[sq * 32 + off + lane] = acc;  // o
    }
  }
  __syncthreads();

  // ---- phase 4: ao = o@Wo, x += rms(ao); h2 = rms(x) -> qbuf ----
  {
    const float4* wo4 = (const float4*)(Wo + e * E_);
#pragma unroll
    for (int k = 0; k < SREG; k++) {
      int s = srow + 8 * k;
      if (S % 8 == 0 || s < S) {
        const float4* o4 = (const float4*)(hbuf + s * 32);
        float a = 0.f;
#pragma unroll
        for (int j = 0; j < 8; j++) {
          float4 oo = o4[j], ww = wo4[j];
          a += oo.x * ww.x + oo.y * ww.y + oo.z * ww.z + oo.w * ww.w;
        }
        float ss = red32(a * a);
        xr[k] += a * rsqrtf(ss * (1.0f / E_) + 1e-6f) * nw1;
        float hx = xr[k];
        float s2s = red32(hx * hx);
        qbuf[s * 32 + e] = hx * rsqrtf(s2s * (1.0f / E_) + 1e-6f) * nw2;
      }
    }
  }
  __syncthreads();

  // ---- phase 5: ffn = silu(h2@Wg) * (h2@Wvl) -> ffnb ----
  {
    const int f = tid & 63;
    const float4* wg4 = (const float4*)(Wg + f * E_);
    const float4* wv4 = (const float4*)(Wvl + f * E_);
    for (int idx = tid; idx < S * FFN_; idx += 256) {
      int s = idx >> 6;
      const float4* h4 = (const float4*)(qbuf + s * 32);
      float g = 0.f, vv = 0.f;
#pragma unroll
      for (int j = 0; j < 8; j++) {
        float4 hh = h4[j];
        float4 a = wg4[j], b = wv4[j];
        g += hh.x * a.x + hh.y * a.y + hh.z * a.z + hh.w * a.w;
        vv += hh.x * b.x + hh.y * b.y + hh.z * b.z + hh.w * b.w;
      }
      float sg = g / (1.0f + __expf(-g));
      ffnb[s * FFN_ + f] = sg * vv;
    }
  }
  __syncthreads();

  // ---- phase 6: out = ffn@Wout^T, x += rms(out), store ----
  {
    const float4* wo2 = (const float4*)(Wout + e * FFN_);
#pragma unroll
    for (int k = 0; k < SREG; k++) {
      int s = srow + 8 * k;
      if (S % 8 == 0 || s < S) {
        const float4* f4 = (const float4*)(ffnb + s * FFN_);
        float a = 0.f;
#pragma unroll
        for (int j = 0; j < 16; j++) {
          float4 ff = f4[j], ww = wo2[j];
          a += ff.x * ww.x + ff.y * ww.y + ff.z * ww.z + ff.w * ww.w;
        }
        float ss = red32(a * a);
        xr[k] += a * rsqrtf(ss * (1.0f / E_) + 1e-6f) * nw3;
        X[base + s * stride + e] = xr[k];
      }
    }
  }
}

// ---------------- final norm + output extraction ----------------
__global__ __launch_bounds__(256) void final_kernel(const float* __restrict__ X,
                                                    const float* __restrict__ fnw,
                                                    float* __restrict__ out) {
  int tok = blockIdx.x * 8 + (threadIdx.x >> 5);
  int e = threadIdx.x & 31;
  if (tok >= B_ * 3) return;
  int b = tok / 3, j = tok % 3;
  const float* xp = X + ((size_t)(b * T_ + (T_ - 1)) * SLOTS_ + OBS_ + j) * E_;
  float v = xp[e];
  float ss = red32(v * v);
  out[j * (B_ * E_) + b * E_ + e] = v * rsqrtf(ss * (1.0f / E_) + 1e-6f) * fnw[e];
}

extern "C" void kernel_launch(void* const* d_in, const int* in_sizes, int n_in,
                              void* d_out, int out_size, void* d_ws, size_t ws_size,
                              hipStream_t stream) {
  (void)in_sizes; (void)n_in; (void)out_size; (void)ws_size;
  const float* obs          = (const float*)d_in[0];
  const float* W_val        = (const float*)d_in[1];
  const float* b_val        = (const float*)d_in[2];
  const float* input_norm_w = (const float*)d_in[3];
  const float* dim_embed    = (const float*)d_in[4];
  const float* cls_tokens   = (const float*)d_in[5];
  const float* final_norm_w = (const float*)d_in[6];
  const float* s_Wq   = (const float*)d_in[7];
  const float* s_Wk   = (const float*)d_in[8];
  const float* s_Wv   = (const float*)d_in[9];
  const float* s_Wo   = (const float*)d_in[10];
  const float* s_Wg   = (const float*)d_in[11];
  const float* s_Wvl  = (const float*)d_in[12];
  const float* s_Wout = (const float*)d_in[13];
  const float* s_n4   = (const float*)d_in[14];
  const float* s_qkn  = (const float*)d_in[15];
  const float* t_Wq   = (const float*)d_in[16];
  const float* t_Wk   = (const float*)d_in[17];
  const float* t_Wv   = (const float*)d_in[18];
  const float* t_Wo   = (const float*)d_in[19];
  const float* t_Wg   = (const float*)d_in[20];
  const float* t_Wvl  = (const float*)d_in[21];
  const float* t_Wout = (const float*)d_in[22];
  const float* t_n4   = (const float*)d_in[23];
  const float* t_qkn  = (const float*)d_in[24];

  float* X = (float*)d_ws;  // B*T*SLOTS*E floats = 17.56 MB
  float* out = (float*)d_out;

  const int total_tokens = B_ * T_ * SLOTS_;
  embed_kernel<<<(total_tokens + 7) / 8, 256, 0, stream>>>(
      obs, W_val, b_val, input_norm_w, dim_embed, cls_tokens, X);

  const int MM = E_ * E_;      // 1024
  const int MF = FFN_ * E_;    // 2048
  const int N4 = 4 * E_;       // 128
  const int QN = 2 * HD_;      // 16

#define SPATIAL(i)                                                              \
  attn_block_kernel<SLOTS_, false><<<B_ * T_, 256, 0, stream>>>(                \
      X, s_Wq + (i)*MM, s_Wk + (i)*MM, s_Wv + (i)*MM, s_Wo + (i)*MM,            \
      s_Wg + (i)*MF, s_Wvl + (i)*MF, s_Wout + (i)*MF, s_n4 + (i)*N4,            \
      s_qkn + (i)*QN)
#define TEMPORAL(i)                                                             \
  attn_block_kernel<T_, true><<<B_ * SLOTS_, 256, 0, stream>>>(                 \
      X, t_Wq + (i)*MM, t_Wk + (i)*MM, t_Wv + (i)*MM, t_Wo + (i)*MM,            \
      t_Wg + (i)*MF, t_Wvl + (i)*MF, t_Wout + (i)*MF, t_n4 + (i)*N4,            \
      t_qkn + (i)*QN)

  SPATIAL(0);
  TEMPORAL(0);
  SPATIAL(1);
  TEMPORAL(1);
  SPATIAL(2);

#undef SPATIAL
#undef TEMPORAL

  final_kernel<<<6, 256, 0, stream>>>(X, final_norm_w, out);
}

// Round 3
// 1027.108 us; speedup vs baseline: 4.0265x; 2.7921x over previous
//
#include <hip/hip_runtime.h>

#define B_ 16
#define T_ 128
#define OBS_ 64
#define SLOTS_ 67
#define E_ 32
#define H_ 4
#define HD_ 8
#define FFN_ 64

typedef _Float16 h2 __attribute__((ext_vector_type(2)));

__device__ __forceinline__ float red32(float v) {
  v += __shfl_xor(v, 16); v += __shfl_xor(v, 8); v += __shfl_xor(v, 4);
  v += __shfl_xor(v, 2);  v += __shfl_xor(v, 1);
  return v;
}
__device__ __forceinline__ float red8(float v) {
  v += __shfl_xor(v, 4); v += __shfl_xor(v, 2); v += __shfl_xor(v, 1);
  return v;
}
__device__ __forceinline__ float fdot2(h2 a, h2 b, float c) {
  return __builtin_amdgcn_fdot2(a, b, c, false);
}

// ---------------- embed + input rmsnorm ----------------
__global__ __launch_bounds__(256) void embed_kernel(
    const float* __restrict__ obs, const float* __restrict__ Wval,
    const float* __restrict__ bval, const float* __restrict__ innw,
    const float* __restrict__ dimemb, const float* __restrict__ cls,
    float* __restrict__ X) {
  int tok = blockIdx.x * 8 + (threadIdx.x >> 5);
  int e = threadIdx.x & 31;
  const int total = B_ * T_ * SLOTS_;
  if (tok >= total) return;
  int slot = tok % SLOTS_;
  int bt = tok / SLOTS_;
  float v;
  if (slot < OBS_) {
    float o = obs[bt * OBS_ + slot];
    v = o * Wval[e] + bval[e] + dimemb[slot * E_ + e];
  } else {
    v = cls[(slot - OBS_) * E_ + e];
  }
  float ss = red32(v * v);
  X[tok * E_ + e] = v * rsqrtf(ss * (1.0f / E_) + 1e-6f) * innw[e];
}

// ---------------- one full attention block per workgroup ----------------
// LDS layout (bytes): [hbuf fp32 S*128 | q fp16 S*64 | k fp16 S*64 | v fp16 S*64]
// ffn (fp16, S*128 B) overlays q+k. Total S*320 B (temporal: 40960 -> 4 blocks/CU).
template <int S, bool TEMPORAL>
__global__ __launch_bounds__(256, 4) void attn_block_kernel(
    float* __restrict__ X,
    const float* __restrict__ Wq, const float* __restrict__ Wk,
    const float* __restrict__ Wv, const float* __restrict__ Wo,
    const float* __restrict__ Wg, const float* __restrict__ Wvl,
    const float* __restrict__ Wout, const float* __restrict__ norm4,
    const float* __restrict__ qkn) {
  constexpr int SREG = (S + 7) / 8;
  __shared__ __align__(16) unsigned char smem[S * 320];
  float* hbuf = (float*)smem;                       // h -> o -> h2
  _Float16* qh = (_Float16*)(smem + S * 128);       // q [s][32]
  _Float16* kh = qh + S * 32;                       // k [s][32]
  _Float16* vh = kh + S * 32;                       // v [s][32]
  _Float16* ffnb = qh;                              // ffn [s][64] overlay

  const int tid = threadIdx.x;
  const int e = tid & 31;
  const int srow = tid >> 5;

  int base, stride;
  if (TEMPORAL) {
    int b = blockIdx.x / SLOTS_;
    int slot = blockIdx.x % SLOTS_;
    base = (b * T_ * SLOTS_ + slot) * E_;
    stride = SLOTS_ * E_;
  } else {
    base = blockIdx.x * S * E_;
    stride = E_;
  }

  const float nw0 = norm4[e], nw1 = norm4[E_ + e], nw2 = norm4[2 * E_ + e],
              nw3 = norm4[3 * E_ + e];

  // ---- phase 1: load x into registers, h = rmsnorm(x) -> hbuf ----
  float xr[SREG];
#pragma unroll
  for (int k = 0; k < SREG; k++) {
    int s = srow + 8 * k;
    if (S % 8 == 0 || s < S) {
      xr[k] = X[base + s * stride + e];
      float ss = red32(xr[k] * xr[k]);
      hbuf[s * 32 + e] = xr[k] * rsqrtf(ss * (1.0f / E_) + 1e-6f) * nw0;
    }
  }
  __syncthreads();

  // ---- phase 2: q/k/v projection + head rmsnorm + RoPE, write fp16 LDS ----
  {
    const int d = e;
    const int hd = d & 7;
    const float qw = qkn[hd], kw = qkn[8 + hd];
    const float isq = 0.35355339059327373f;  // folded into stored q
    float theta = 0.f;
    if (TEMPORAL) theta = exp2f(-(float)(hd & 3) * 3.3219280948873623f);
    const float4* wq4 = (const float4*)(Wq + d * E_);
    const float4* wk4 = (const float4*)(Wk + d * E_);
    const float4* wv4 = (const float4*)(Wv + d * E_);
    for (int idx = tid; idx < S * E_; idx += 256) {
      int s = idx >> 5;
      const float4* h4 = (const float4*)(hbuf + s * 32);
      float aq = 0.f, ak = 0.f, av = 0.f;
#pragma unroll
      for (int j = 0; j < 8; j++) {
        float4 hh = h4[j];
        float4 a = wq4[j], b = wk4[j], c = wv4[j];
        aq += hh.x * a.x + hh.y * a.y + hh.z * a.z + hh.w * a.w;
        ak += hh.x * b.x + hh.y * b.y + hh.z * b.z + hh.w * b.w;
        av += hh.x * c.x + hh.y * c.y + hh.z * c.z + hh.w * c.w;
      }
      float qss = red8(aq * aq);
      float kss = red8(ak * ak);
      float qv = aq * rsqrtf(qss * (1.0f / HD_) + 1e-6f) * qw;
      float kv = ak * rsqrtf(kss * (1.0f / HD_) + 1e-6f) * kw;
      if (TEMPORAL) {
        float ang = (float)s * theta;
        float c, sn;
        __sincosf(ang, &sn, &c);
        float qp = __shfl_xor(qv, 4);
        float kp = __shfl_xor(kv, 4);
        qv = (hd < 4) ? (qv * c - qp * sn) : (qv * c + qp * sn);
        kv = (hd < 4) ? (kv * c - kp * sn) : (kv * c + kp * sn);
      }
      qh[s * 32 + d] = (_Float16)(qv * isq);
      kh[s * 32 + d] = (_Float16)kv;
      vh[s * 32 + d] = (_Float16)av;
    }
  }
  __syncthreads();

  // ---- phase 3: attention; wave = head, lane = query; no shuffles/barriers ----
  {
    const int head = tid >> 6, lane = tid & 63;
    const h2* q2base = (const h2*)qh;  // token s, head h at [s*16 + h*4]
    const h2* k2base = (const h2*)kh;
    const h2* v2base = (const h2*)vh;
    constexpr int NB = (S + 63) / 64;
#pragma unroll
    for (int b = 0; b < NB; b++) {
      int sq = b * 64 + lane;
      bool act = (S % 64 == 0) || (sq < S);
      int sqc = act ? sq : 0;
      const h2* qp = q2base + sqc * 16 + head * 4;
      h2 q0 = qp[0], q1 = qp[1], q2 = qp[2], q3 = qp[3];
      float m = -1e30f;
#pragma unroll 8
      for (int k = 0; k < S; k++) {
        const h2* kk = k2base + k * 16 + head * 4;
        float sc = fdot2(q0, kk[0], fdot2(q1, kk[1], fdot2(q2, kk[2], fdot2(q3, kk[3], 0.f))));
        m = fmaxf(m, sc);
      }
      float l = 0.f;
      h2 a0 = {(_Float16)0.f, (_Float16)0.f}, a1 = a0, a2 = a0, a3 = a0;
#pragma unroll 8
      for (int k = 0; k < S; k++) {
        const h2* kk = k2base + k * 16 + head * 4;
        float sc = fdot2(q0, kk[0], fdot2(q1, kk[1], fdot2(q2, kk[2], fdot2(q3, kk[3], 0.f))));
        float ev = __expf(sc - m);
        l += ev;
        _Float16 ph = (_Float16)ev;
        h2 p2 = {ph, ph};
        const h2* vv = v2base + k * 16 + head * 4;
        a0 += p2 * vv[0]; a1 += p2 * vv[1]; a2 += p2 * vv[2]; a3 += p2 * vv[3];
      }
      float invl = 1.0f / l;
      if (act) {
        float4 o0, o1;
        o0.x = (float)a0.x * invl; o0.y = (float)a0.y * invl;
        o0.z = (float)a1.x * invl; o0.w = (float)a1.y * invl;
        o1.x = (float)a2.x * invl; o1.y = (float)a2.y * invl;
        o1.z = (float)a3.x * invl; o1.w = (float)a3.y * invl;
        float4* op = (float4*)(hbuf + sq * 32 + head * 8);
        op[0] = o0; op[1] = o1;
      }
    }
  }
  __syncthreads();

  // ---- phase 4: ao = o@Wo, x += rms(ao); h2 = rms(x) -> hbuf ----
  {
    const float4* wo4 = (const float4*)(Wo + e * E_);
    float h2v[SREG];
#pragma unroll
    for (int k = 0; k < SREG; k++) {
      int s = srow + 8 * k;
      if (S % 8 == 0 || s < S) {
        const float4* o4 = (const float4*)(hbuf + s * 32);
        float a = 0.f;
#pragma unroll
        for (int j = 0; j < 8; j++) {
          float4 oo = o4[j], ww = wo4[j];
          a += oo.x * ww.x + oo.y * ww.y + oo.z * ww.z + oo.w * ww.w;
        }
        float ss = red32(a * a);
        xr[k] += a * rsqrtf(ss * (1.0f / E_) + 1e-6f) * nw1;
        float hx = xr[k];
        float s2s = red32(hx * hx);
        h2v[k] = hx * rsqrtf(s2s * (1.0f / E_) + 1e-6f) * nw2;
      }
    }
    // write h2 after all o-reads of this wave's rows are done (wave-lockstep per row)
#pragma unroll
    for (int k = 0; k < SREG; k++) {
      int s = srow + 8 * k;
      if (S % 8 == 0 || s < S) hbuf[s * 32 + e] = h2v[k];
    }
  }
  __syncthreads();

  // ---- phase 5: ffn = silu(h2@Wg) * (h2@Wvl) -> ffnb (fp16) ----
  {
    const int f = tid & 63;
    const float4* wg4 = (const float4*)(Wg + f * E_);
    const float4* wv4 = (const float4*)(Wvl + f * E_);
    for (int idx = tid; idx < S * FFN_; idx += 256) {
      int s = idx >> 6;
      const float4* h4 = (const float4*)(hbuf + s * 32);
      float g = 0.f, vv = 0.f;
#pragma unroll
      for (int j = 0; j < 8; j++) {
        float4 hh = h4[j];
        float4 a = wg4[j], b = wv4[j];
        g += hh.x * a.x + hh.y * a.y + hh.z * a.z + hh.w * a.w;
        vv += hh.x * b.x + hh.y * b.y + hh.z * b.z + hh.w * b.w;
      }
      float sg = g / (1.0f + __expf(-g));
      ffnb[s * FFN_ + f] = (_Float16)(sg * vv);
    }
  }
  __syncthreads();

  // ---- phase 6: out = ffn@Wout^T (fdot2), x += rms(out), store ----
  {
    // convert this thread's Wout row to fp16 once (32 half2 regs)
    const float2* w2 = (const float2*)(Wout + e * FFN_);
    h2 wh[32];
#pragma unroll
    for (int j = 0; j < 32; j++) {
      float2 w = w2[j];
      wh[j] = (h2){(_Float16)w.x, (_Float16)w.y};
    }
#pragma unroll
    for (int k = 0; k < SREG; k++) {
      int s = srow + 8 * k;
      if (S % 8 == 0 || s < S) {
        const h2* f2 = (const h2*)(ffnb + s * FFN_);
        float p0 = 0.f, p1 = 0.f, p2 = 0.f, p3 = 0.f;
#pragma unroll
        for (int j = 0; j < 32; j += 4) {
          p0 = fdot2(f2[j], wh[j], p0);
          p1 = fdot2(f2[j + 1], wh[j + 1], p1);
          p2 = fdot2(f2[j + 2], wh[j + 2], p2);
          p3 = fdot2(f2[j + 3], wh[j + 3], p3);
        }
        float a = (p0 + p1) + (p2 + p3);
        float ss = red32(a * a);
        xr[k] += a * rsqrtf(ss * (1.0f / E_) + 1e-6f) * nw3;
        X[base + s * stride + e] = xr[k];
      }
    }
  }
}

// ---------------- final norm + output extraction ----------------
__global__ __launch_bounds__(256) void final_kernel(const float* __restrict__ X,
                                                    const float* __restrict__ fnw,
                                                    float* __restrict__ out) {
  int tok = blockIdx.x * 8 + (threadIdx.x >> 5);
  int e = threadIdx.x & 31;
  if (tok >= B_ * 3) return;
  int b = tok / 3, j = tok % 3;
  const float* xp = X + ((size_t)(b * T_ + (T_ - 1)) * SLOTS_ + OBS_ + j) * E_;
  float v = xp[e];
  float ss = red32(v * v);
  out[j * (B_ * E_) + b * E_ + e] = v * rsqrtf(ss * (1.0f / E_) + 1e-6f) * fnw[e];
}

extern "C" void kernel_launch(void* const* d_in, const int* in_sizes, int n_in,
                              void* d_out, int out_size, void* d_ws, size_t ws_size,
                              hipStream_t stream) {
  (void)in_sizes; (void)n_in; (void)out_size; (void)ws_size;
  const float* obs          = (const float*)d_in[0];
  const float* W_val        = (const float*)d_in[1];
  const float* b_val        = (const float*)d_in[2];
  const float* input_norm_w = (const float*)d_in[3];
  const float* dim_embed    = (const float*)d_in[4];
  const float* cls_tokens   = (const float*)d_in[5];
  const float* final_norm_w = (const float*)d_in[6];
  const float* s_Wq   = (const float*)d_in[7];
  const float* s_Wk   = (const float*)d_in[8];
  const float* s_Wv   = (const float*)d_in[9];
  const float* s_Wo   = (const float*)d_in[10];
  const float* s_Wg   = (const float*)d_in[11];
  const float* s_Wvl  = (const float*)d_in[12];
  const float* s_Wout = (const float*)d_in[13];
  const float* s_n4   = (const float*)d_in[14];
  const float* s_qkn  = (const float*)d_in[15];
  const float* t_Wq   = (const float*)d_in[16];
  const float* t_Wk   = (const float*)d_in[17];
  const float* t_Wv   = (const float*)d_in[18];
  const float* t_Wo   = (const float*)d_in[19];
  const float* t_Wg   = (const float*)d_in[20];
  const float* t_Wvl  = (const float*)d_in[21];
  const float* t_Wout = (const float*)d_in[22];
  const float* t_n4   = (const float*)d_in[23];
  const float* t_qkn  = (const float*)d_in[24];

  float* X = (float*)d_ws;  // B*T*SLOTS*E floats = 17.56 MB
  float* out = (float*)d_out;

  const int total_tokens = B_ * T_ * SLOTS_;
  embed_kernel<<<(total_tokens + 7) / 8, 256, 0, stream>>>(
      obs, W_val, b_val, input_norm_w, dim_embed, cls_tokens, X);

  const int MM = E_ * E_;      // 1024
  const int MF = FFN_ * E_;    // 2048
  const int N4 = 4 * E_;       // 128
  const int QN = 2 * HD_;      // 16

#define SPATIAL(i)                                                              \
  attn_block_kernel<SLOTS_, false><<<B_ * T_, 256, 0, stream>>>(                \
      X, s_Wq + (i)*MM, s_Wk + (i)*MM, s_Wv + (i)*MM, s_Wo + (i)*MM,            \
      s_Wg + (i)*MF, s_Wvl + (i)*MF, s_Wout + (i)*MF, s_n4 + (i)*N4,            \
      s_qkn + (i)*QN)
#define TEMPORAL(i)                                                             \
  attn_block_kernel<T_, true><<<B_ * SLOTS_, 256, 0, stream>>>(                 \
      X, t_Wq + (i)*MM, t_Wk + (i)*MM, t_Wv + (i)*MM, t_Wo + (i)*MM,            \
      t_Wg + (i)*MF, t_Wvl + (i)*MF, t_Wout + (i)*MF, t_n4 + (i)*N4,            \
      t_qkn + (i)*QN)

  SPATIAL(0);
  TEMPORAL(0);
  SPATIAL(1);
  TEMPORAL(1);
  SPATIAL(2);

#undef SPATIAL
#undef TEMPORAL

  final_kernel<<<6, 256, 0, stream>>>(X, final_norm_w, out);
}

// Round 5
// 635.541 us; speedup vs baseline: 6.5073x; 1.6161x over previous
//
#include <hip/hip_runtime.h>

#define B_ 16
#define T_ 128
#define OBS_ 64
#define SLOTS_ 67
#define E_ 32
#define H_ 4
#define HD_ 8
#define FFN_ 64

typedef _Float16 h2 __attribute__((ext_vector_type(2)));
typedef _Float16 h8 __attribute__((ext_vector_type(8)));
union H8 { h8 v; h2 h[4]; };

__device__ __forceinline__ float red32(float v) {
  v += __shfl_xor(v, 16); v += __shfl_xor(v, 8); v += __shfl_xor(v, 4);
  v += __shfl_xor(v, 2);  v += __shfl_xor(v, 1);
  return v;
}
__device__ __forceinline__ float red8(float v) {
  v += __shfl_xor(v, 4); v += __shfl_xor(v, 2); v += __shfl_xor(v, 1);
  return v;
}
__device__ __forceinline__ float fdot2(h2 a, h2 b, float c) {
  return __builtin_amdgcn_fdot2(a, b, c, false);
}
__device__ __forceinline__ h2 pkrtz(float x, float y) {
  return __builtin_bit_cast(h2, __builtin_amdgcn_cvt_pkrtz(x, y));
}

// ---------------- embed + input rmsnorm ----------------
__global__ __launch_bounds__(256) void embed_kernel(
    const float* __restrict__ obs, const float* __restrict__ Wval,
    const float* __restrict__ bval, const float* __restrict__ innw,
    const float* __restrict__ dimemb, const float* __restrict__ cls,
    float* __restrict__ X) {
  int tok = blockIdx.x * 8 + (threadIdx.x >> 5);
  int e = threadIdx.x & 31;
  const int total = B_ * T_ * SLOTS_;
  if (tok >= total) return;
  int slot = tok % SLOTS_;
  int bt = tok / SLOTS_;
  float v;
  if (slot < OBS_) {
    float o = obs[bt * OBS_ + slot];
    v = o * Wval[e] + bval[e] + dimemb[slot * E_ + e];
  } else {
    v = cls[(slot - OBS_) * E_ + e];
  }
  float ss = red32(v * v);
  X[tok * E_ + e] = v * rsqrtf(ss * (1.0f / E_) + 1e-6f) * innw[e];
}

// ---------------- one full attention block per workgroup ----------------
// LDS (halves): [hbuf S*32 | q S*32 | k S*32 | v S*32]; ffn (S*64) overlays q+k.
// hbuf: h -> o -> h2(ffn input). Temporal: 32 KB -> up to 5 blocks/CU.
template <int S, bool TEMPORAL>
__global__ __launch_bounds__(256, 4) void attn_block_kernel(
    float* __restrict__ X,
    const float* __restrict__ Wq, const float* __restrict__ Wk,
    const float* __restrict__ Wv, const float* __restrict__ Wo,
    const float* __restrict__ Wg, const float* __restrict__ Wvl,
    const float* __restrict__ Wout, const float* __restrict__ norm4,
    const float* __restrict__ qkn) {
  constexpr int SREG = (S + 7) / 8;
  __shared__ __align__(16) _Float16 smem[S * 128];
  _Float16* hbuf = smem;            // h -> o -> h2
  _Float16* qh = smem + S * 32;
  _Float16* kh = smem + S * 64;
  _Float16* vh = smem + S * 96;
  _Float16* ffnb = qh;              // ffn overlay (S*64 halves over q+k)

  const int tid = threadIdx.x;
  const int e = tid & 31;
  const int srow = tid >> 5;

  int base, stride;
  if (TEMPORAL) {
    int b = blockIdx.x / SLOTS_;
    int slot = blockIdx.x % SLOTS_;
    base = (b * T_ * SLOTS_ + slot) * E_;
    stride = SLOTS_ * E_;
  } else {
    base = blockIdx.x * S * E_;
    stride = E_;
  }

  const float nw0 = norm4[e], nw1 = norm4[E_ + e], nw2 = norm4[2 * E_ + e],
              nw3 = norm4[3 * E_ + e];

  // ---- phase 1: x -> regs; h = rmsnorm(x) -> hbuf (fp16) ----
  float xr[SREG];
#pragma unroll
  for (int k = 0; k < SREG; k++) {
    int s = srow + 8 * k;
    if (S % 8 == 0 || s < S) {
      xr[k] = X[base + s * stride + e];
      float ss = red32(xr[k] * xr[k]);
      hbuf[s * 32 + e] = (_Float16)(xr[k] * rsqrtf(ss * (1.0f / E_) + 1e-6f) * nw0);
    }
  }
  __syncthreads();

  // ---- phase 2: q/k/v projection (fdot2) + head rmsnorm + RoPE ----
  {
    const int d = e;
    const int hd = d & 7;
    const float qw = qkn[hd], kw = qkn[8 + hd];
    const float qscale = 0.35355339059327373f * 1.4426950408889634f;  // 1/sqrt(8)*log2e
    float theta = 0.f;
    if (TEMPORAL) theta = exp2f(-(float)(hd & 3) * 3.3219280948873623f);
    h2 wq[16], wk[16], wv[16];
    {
      const float4* a4 = (const float4*)(Wq + d * E_);
      const float4* b4 = (const float4*)(Wk + d * E_);
      const float4* c4 = (const float4*)(Wv + d * E_);
#pragma unroll
      for (int j = 0; j < 8; j++) {
        float4 a = a4[j], b = b4[j], c = c4[j];
        wq[2 * j] = pkrtz(a.x, a.y); wq[2 * j + 1] = pkrtz(a.z, a.w);
        wk[2 * j] = pkrtz(b.x, b.y); wk[2 * j + 1] = pkrtz(b.z, b.w);
        wv[2 * j] = pkrtz(c.x, c.y); wv[2 * j + 1] = pkrtz(c.z, c.w);
      }
    }
    for (int idx = tid; idx < S * E_; idx += 256) {
      int s = idx >> 5;
      const H8* hrow = (const H8*)(hbuf + s * 32);
      float aq = 0.f, ak = 0.f, av = 0.f;
#pragma unroll
      for (int c = 0; c < 4; c++) {
        H8 hc = hrow[c];
#pragma unroll
        for (int j = 0; j < 4; j++) {
          aq = fdot2(hc.h[j], wq[4 * c + j], aq);
          ak = fdot2(hc.h[j], wk[4 * c + j], ak);
          av = fdot2(hc.h[j], wv[4 * c + j], av);
        }
      }
      float qss = red8(aq * aq);
      float kss = red8(ak * ak);
      float qv = aq * rsqrtf(qss * (1.0f / HD_) + 1e-6f) * qw;
      float kv = ak * rsqrtf(kss * (1.0f / HD_) + 1e-6f) * kw;
      if (TEMPORAL) {
        float ang = (float)s * theta;
        float c, sn;
        __sincosf(ang, &sn, &c);
        float qp = __shfl_xor(qv, 4);
        float kp = __shfl_xor(kv, 4);
        qv = (hd < 4) ? (qv * c - qp * sn) : (qv * c + qp * sn);
        kv = (hd < 4) ? (kv * c - kp * sn) : (kv * c + kp * sn);
      }
      qh[s * 32 + d] = (_Float16)(qv * qscale);  // exp2-ready
      kh[s * 32 + d] = (_Float16)kv;
      vh[s * 32 + d] = (_Float16)av;
    }
  }
  __syncthreads();

  // ---- phase 3: attention, single-pass softmax (scores bounded by sqrt(8)) ----
  // thread g owns query g>>1, head pair g&1. No shuffles, no barriers.
  {
    const int g = tid;
    if (2 * g < 4 * S) {
      const int qi = g >> 1;
      const int hp = g & 1;  // head pair
      const _Float16* qp = qh + qi * 32 + hp * 16;
      H8 qa, qb;
      qa.v = *(const h8*)qp;
      qb.v = *(const h8*)(qp + 8);
      float l0 = 0.f, l1 = 0.f;
      h2 acc[8] = {};
      const _Float16* kp = kh + hp * 16;
      const _Float16* vp = vh + hp * 16;
#pragma unroll 4
      for (int k = 0; k < S; k++) {
        H8 ka, kb, va, vb;
        ka.v = *(const h8*)kp;
        kb.v = *(const h8*)(kp + 8);
        va.v = *(const h8*)vp;
        vb.v = *(const h8*)(vp + 8);
        kp += 32; vp += 32;
        float s0 = fdot2(qa.h[0], ka.h[0], fdot2(qa.h[1], ka.h[1],
                   fdot2(qa.h[2], ka.h[2], fdot2(qa.h[3], ka.h[3], 0.f))));
        float s1 = fdot2(qb.h[0], kb.h[0], fdot2(qb.h[1], kb.h[1],
                   fdot2(qb.h[2], kb.h[2], fdot2(qb.h[3], kb.h[3], 0.f))));
        float e0 = __builtin_amdgcn_exp2f(s0);
        float e1 = __builtin_amdgcn_exp2f(s1);
        l0 += e0; l1 += e1;
        h2 p0 = pkrtz(e0, e0);
        h2 p1 = pkrtz(e1, e1);
        acc[0] += p0 * va.h[0]; acc[1] += p0 * va.h[1];
        acc[2] += p0 * va.h[2]; acc[3] += p0 * va.h[3];
        acc[4] += p1 * vb.h[0]; acc[5] += p1 * vb.h[1];
        acc[6] += p1 * vb.h[2]; acc[7] += p1 * vb.h[3];
      }
      float iv0 = 1.0f / l0, iv1 = 1.0f / l1;
      h2 il0 = pkrtz(iv0, iv0), il1 = pkrtz(iv1, iv1);
      H8 o0, o1;
#pragma unroll
      for (int j = 0; j < 4; j++) {
        o0.h[j] = acc[j] * il0;
        o1.h[j] = acc[4 + j] * il1;
      }
      _Float16* op = hbuf + qi * 32 + hp * 16;
      *(h8*)op = o0.v;
      *(h8*)(op + 8) = o1.v;
    }
  }
  __syncthreads();

  // ---- phase 4: ao = o@Wo, x += rms(ao); h2 = rms(x) -> hbuf ----
  {
    h2 wo[16];
    {
      const float4* w4 = (const float4*)(Wo + e * E_);
#pragma unroll
      for (int j = 0; j < 8; j++) {
        float4 w = w4[j];
        wo[2 * j] = pkrtz(w.x, w.y);
        wo[2 * j + 1] = pkrtz(w.z, w.w);
      }
    }
#pragma unroll
    for (int k = 0; k < SREG; k++) {
      int s = srow + 8 * k;
      if (S % 8 == 0 || s < S) {
        const H8* orow = (const H8*)(hbuf + s * 32);
        float a = 0.f;
#pragma unroll
        for (int c = 0; c < 4; c++) {
          H8 oc = orow[c];
#pragma unroll
          for (int j = 0; j < 4; j++) a = fdot2(oc.h[j], wo[4 * c + j], a);
        }
        float ss = red32(a * a);
        xr[k] += a * rsqrtf(ss * (1.0f / E_) + 1e-6f) * nw1;
        float hx = xr[k];
        float s2s = red32(hx * hx);
        // row s touched only by this half-wave; lockstep => write-after-read safe
        hbuf[s * 32 + e] = (_Float16)(hx * rsqrtf(s2s * (1.0f / E_) + 1e-6f) * nw2);
      }
    }
  }
  __syncthreads();

  // ---- phase 5: ffn = silu(h2@Wg) * (h2@Wvl) -> ffnb (fp16) ----
  {
    const int f = tid & 63;
    h2 wg[16], wl[16];
    {
      const float4* a4 = (const float4*)(Wg + f * E_);
      const float4* b4 = (const float4*)(Wvl + f * E_);
#pragma unroll
      for (int j = 0; j < 8; j++) {
        float4 a = a4[j], b = b4[j];
        wg[2 * j] = pkrtz(a.x, a.y); wg[2 * j + 1] = pkrtz(a.z, a.w);
        wl[2 * j] = pkrtz(b.x, b.y); wl[2 * j + 1] = pkrtz(b.z, b.w);
      }
    }
    for (int idx = tid; idx < S * FFN_; idx += 256) {
      int s = idx >> 6;
      const H8* hrow = (const H8*)(hbuf + s * 32);
      float g = 0.f, vv = 0.f;
#pragma unroll
      for (int c = 0; c < 4; c++) {
        H8 hc = hrow[c];
#pragma unroll
        for (int j = 0; j < 4; j++) {
          g = fdot2(hc.h[j], wg[4 * c + j], g);
          vv = fdot2(hc.h[j], wl[4 * c + j], vv);
        }
      }
      float sg = g / (1.0f + __expf(-g));
      ffnb[s * FFN_ + f] = (_Float16)(sg * vv);
    }
  }
  __syncthreads();

  // ---- phase 6: out = ffn@Wout^T, x += rms(out), store ----
  {
    h2 wh[32];
    {
      const float4* w4 = (const float4*)(Wout + e * FFN_);
#pragma unroll
      for (int j = 0; j < 16; j++) {
        float4 w = w4[j];
        wh[2 * j] = pkrtz(w.x, w.y);
        wh[2 * j + 1] = pkrtz(w.z, w.w);
      }
    }
#pragma unroll
    for (int k = 0; k < SREG; k++) {
      int s = srow + 8 * k;
      if (S % 8 == 0 || s < S) {
        const H8* frow = (const H8*)(ffnb + s * FFN_);
        float p0 = 0.f, p1 = 0.f, p2 = 0.f, p3 = 0.f;
#pragma unroll
        for (int c = 0; c < 8; c++) {
          H8 fc = frow[c];
          p0 = fdot2(fc.h[0], wh[4 * c + 0], p0);
          p1 = fdot2(fc.h[1], wh[4 * c + 1], p1);
          p2 = fdot2(fc.h[2], wh[4 * c + 2], p2);
          p3 = fdot2(fc.h[3], wh[4 * c + 3], p3);
        }
        float a = (p0 + p1) + (p2 + p3);
        float ss = red32(a * a);
        xr[k] += a * rsqrtf(ss * (1.0f / E_) + 1e-6f) * nw3;
        X[base + s * stride + e] = xr[k];
      }
    }
  }
}

// ---------------- final norm + output extraction ----------------
__global__ __launch_bounds__(256) void final_kernel(const float* __restrict__ X,
                                                    const float* __restrict__ fnw,
                                                    float* __restrict__ out) {
  int tok = blockIdx.x * 8 + (threadIdx.x >> 5);
  int e = threadIdx.x & 31;
  if (tok >= B_ * 3) return;
  int b = tok / 3, j = tok % 3;
  const float* xp = X + ((size_t)(b * T_ + (T_ - 1)) * SLOTS_ + OBS_ + j) * E_;
  float v = xp[e];
  float ss = red32(v * v);
  out[j * (B_ * E_) + b * E_ + e] = v * rsqrtf(ss * (1.0f / E_) + 1e-6f) * fnw[e];
}

extern "C" void kernel_launch(void* const* d_in, const int* in_sizes, int n_in,
                              void* d_out, int out_size, void* d_ws, size_t ws_size,
                              hipStream_t stream) {
  (void)in_sizes; (void)n_in; (void)out_size; (void)ws_size;
  const float* obs          = (const float*)d_in[0];
  const float* W_val        = (const float*)d_in[1];
  const float* b_val        = (const float*)d_in[2];
  const float* input_norm_w = (const float*)d_in[3];
  const float* dim_embed    = (const float*)d_in[4];
  const float* cls_tokens   = (const float*)d_in[5];
  const float* final_norm_w = (const float*)d_in[6];
  const float* s_Wq   = (const float*)d_in[7];
  const float* s_Wk   = (const float*)d_in[8];
  const float* s_Wv   = (const float*)d_in[9];
  const float* s_Wo   = (const float*)d_in[10];
  const float* s_Wg   = (const float*)d_in[11];
  const float* s_Wvl  = (const float*)d_in[12];
  const float* s_Wout = (const float*)d_in[13];
  const float* s_n4   = (const float*)d_in[14];
  const float* s_qkn  = (const float*)d_in[15];
  const float* t_Wq   = (const float*)d_in[16];
  const float* t_Wk   = (const float*)d_in[17];
  const float* t_Wv   = (const float*)d_in[18];
  const float* t_Wo   = (const float*)d_in[19];
  const float* t_Wg   = (const float*)d_in[20];
  const float* t_Wvl  = (const float*)d_in[21];
  const float* t_Wout = (const float*)d_in[22];
  const float* t_n4   = (const float*)d_in[23];
  const float* t_qkn  = (const float*)d_in[24];

  float* X = (float*)d_ws;  // B*T*SLOTS*E floats = 17.56 MB
  float* out = (float*)d_out;

  const int total_tokens = B_ * T_ * SLOTS_;
  embed_kernel<<<(total_tokens + 7) / 8, 256, 0, stream>>>(
      obs, W_val, b_val, input_norm_w, dim_embed, cls_tokens, X);

  const int MM = E_ * E_;      // 1024
  const int MF = FFN_ * E_;    // 2048
  const int N4 = 4 * E_;       // 128
  const int QN = 2 * HD_;      // 16

#define SPATIAL(i)                                                              \
  attn_block_kernel<SLOTS_, false><<<B_ * T_, 256, 0, stream>>>(                \
      X, s_Wq + (i)*MM, s_Wk + (i)*MM, s_Wv + (i)*MM, s_Wo + (i)*MM,            \
      s_Wg + (i)*MF, s_Wvl + (i)*MF, s_Wout + (i)*MF, s_n4 + (i)*N4,            \
      s_qkn + (i)*QN)
#define TEMPORAL(i)                                                             \
  attn_block_kernel<T_, true><<<B_ * SLOTS_, 256, 0, stream>>>(                 \
      X, t_Wq + (i)*MM, t_Wk + (i)*MM, t_Wv + (i)*MM, t_Wo + (i)*MM,            \
      t_Wg + (i)*MF, t_Wvl + (i)*MF, t_Wout + (i)*MF, t_n4 + (i)*N4,            \
      t_qkn + (i)*QN)

  SPATIAL(0);
  TEMPORAL(0);
  SPATIAL(1);
  TEMPORAL(1);
  SPATIAL(2);

#undef SPATIAL
#undef TEMPORAL

  final_kernel<<<6, 256, 0, stream>>>(X, final_norm_w, out);
}

// Round 6
// 570.602 us; speedup vs baseline: 7.2479x; 1.1138x over previous
//
#include <hip/hip_runtime.h>

#define B_ 16
#define T_ 128
#define OBS_ 64
#define SLOTS_ 67
#define E_ 32
#define H_ 4
#define HD_ 8
#define FFN_ 64

typedef _Float16 h2 __attribute__((ext_vector_type(2)));
typedef _Float16 h8 __attribute__((ext_vector_type(8)));
union H8 { h8 v; h2 h[4]; };

// fp16 weight block layout (halves): Wq 0 | Wk 1024 | Wv 2048 | Wo 3072 |
// Wg 4096 | Wvl 6144 | Wout 8192  (10240 halves per transformer block)
#define WBLK 10240
#define X_BYTES (B_ * T_ * SLOTS_ * E_ * 4)  // 17,563,648

__device__ __forceinline__ float red32(float v) {
  v += __shfl_xor(v, 16); v += __shfl_xor(v, 8); v += __shfl_xor(v, 4);
  v += __shfl_xor(v, 2);  v += __shfl_xor(v, 1);
  return v;
}
__device__ __forceinline__ float red8(float v) {
  v += __shfl_xor(v, 4); v += __shfl_xor(v, 2); v += __shfl_xor(v, 1);
  return v;
}
__device__ __forceinline__ float fdot2(h2 a, h2 b, float c) {
  return __builtin_amdgcn_fdot2(a, b, c, false);
}
__device__ __forceinline__ h2 pkrtz(float x, float y) {
  return __builtin_bit_cast(h2, __builtin_amdgcn_cvt_pkrtz(x, y));
}

// ---------------- weight pre-conversion to fp16 ----------------
struct WPtrs {
  const float *sWq, *sWk, *sWv, *sWo, *sWg, *sWvl, *sWout;
  const float *tWq, *tWk, *tWv, *tWo, *tWg, *tWvl, *tWout;
};

__global__ __launch_bounds__(256) void cvt_weights_kernel(WPtrs p, _Float16* dst) {
  int i = blockIdx.x * 256 + threadIdx.x;  // pair index
  const int total_pairs = 5 * WBLK / 2;    // 25600
  if (i >= total_pairs) return;
  int blk = i / (WBLK / 2);
  int f = (i % (WBLK / 2)) * 2;  // float offset within block's 10240
  bool sp = blk < 3;
  int bi = sp ? blk : blk - 3;
  const float* src;
  int o;
  if (f < 1024)      { src = (sp ? p.sWq : p.tWq) + bi * 1024;  o = f; }
  else if (f < 2048) { src = (sp ? p.sWk : p.tWk) + bi * 1024;  o = f - 1024; }
  else if (f < 3072) { src = (sp ? p.sWv : p.tWv) + bi * 1024;  o = f - 2048; }
  else if (f < 4096) { src = (sp ? p.sWo : p.tWo) + bi * 1024;  o = f - 3072; }
  else if (f < 6144) { src = (sp ? p.sWg : p.tWg) + bi * 2048;  o = f - 4096; }
  else if (f < 8192) { src = (sp ? p.sWvl : p.tWvl) + bi * 2048; o = f - 6144; }
  else               { src = (sp ? p.sWout : p.tWout) + bi * 2048; o = f - 8192; }
  ((h2*)dst)[i] = pkrtz(src[o], src[o + 1]);
}

// ---------------- embed + input rmsnorm ----------------
__global__ __launch_bounds__(256) void embed_kernel(
    const float* __restrict__ obs, const float* __restrict__ Wval,
    const float* __restrict__ bval, const float* __restrict__ innw,
    const float* __restrict__ dimemb, const float* __restrict__ cls,
    float* __restrict__ X) {
  int tok = blockIdx.x * 8 + (threadIdx.x >> 5);
  int e = threadIdx.x & 31;
  const int total = B_ * T_ * SLOTS_;
  if (tok >= total) return;
  int slot = tok % SLOTS_;
  int bt = tok / SLOTS_;
  float v;
  if (slot < OBS_) {
    float o = obs[bt * OBS_ + slot];
    v = o * Wval[e] + bval[e] + dimemb[slot * E_ + e];
  } else {
    v = cls[(slot - OBS_) * E_ + e];
  }
  float ss = red32(v * v);
  X[tok * E_ + e] = v * rsqrtf(ss * (1.0f / E_) + 1e-6f) * innw[e];
}

// ---------------- one full attention block per workgroup ----------------
// LDS (halves): [hbuf S*32 | qbuf S*32 | kbuf S*32].
// hbuf: h -> o -> h2. qbuf: q -> v. ffn (S*64) overlays qbuf+kbuf.
// Temporal: 24576 B -> 6 blocks/CU; spatial: 12864 B -> 8 blocks/CU (wave cap).
template <int S, bool TEMPORAL>
__global__ __launch_bounds__(256, 8) void attn_block_kernel(
    float* __restrict__ X, const _Float16* __restrict__ W16,
    const float* __restrict__ norm4, const float* __restrict__ qkn) {
  constexpr int SREG = (S + 7) / 8;
  __shared__ __align__(16) _Float16 smem[S * 96];
  _Float16* hbuf = smem;            // h -> o -> h2
  _Float16* qh = smem + S * 32;     // q -> v
  _Float16* kh = smem + S * 64;     // k
  _Float16* ffnb = qh;              // ffn overlay (S*64 halves)

  const int tid = threadIdx.x;
  const int e = tid & 31;
  const int srow = tid >> 5;

  int base, stride;
  if (TEMPORAL) {
    int b = blockIdx.x / SLOTS_;
    int slot = blockIdx.x % SLOTS_;
    base = (b * T_ * SLOTS_ + slot) * E_;
    stride = SLOTS_ * E_;
  } else {
    base = blockIdx.x * S * E_;
    stride = E_;
  }

  const float nw0 = norm4[e], nw1 = norm4[E_ + e], nw2 = norm4[2 * E_ + e],
              nw3 = norm4[3 * E_ + e];

  // ---- phase 1: x -> regs; h = rmsnorm(x) -> hbuf (fp16) ----
  float xr[SREG];
#pragma unroll
  for (int k = 0; k < SREG; k++) {
    int s = srow + 8 * k;
    if (S % 8 == 0 || s < S) {
      xr[k] = X[base + s * stride + e];
      float ss = red32(xr[k] * xr[k]);
      hbuf[s * 32 + e] = (_Float16)(xr[k] * rsqrtf(ss * (1.0f / E_) + 1e-6f) * nw0);
    }
  }
  __syncthreads();

  // ---- phase 2: q/k projection + head rmsnorm + RoPE -> qh, kh ----
  {
    const int d = e;
    const int hd = d & 7;
    const float qw = qkn[hd], kw = qkn[8 + hd];
    const float qscale = 0.35355339059327373f * 1.4426950408889634f;  // 1/sqrt(8)*log2e
    float theta = 0.f;
    if (TEMPORAL) theta = exp2f(-(float)(hd & 3) * 3.3219280948873623f);
    H8 wq[4], wk[4];
    {
      const h8* wqp = (const h8*)(W16 + d * 32);
      const h8* wkp = (const h8*)(W16 + 1024 + d * 32);
#pragma unroll
      for (int j = 0; j < 4; j++) { wq[j].v = wqp[j]; wk[j].v = wkp[j]; }
    }
    for (int idx = tid; idx < S * E_; idx += 256) {
      int s = idx >> 5;
      const H8* hrow = (const H8*)(hbuf + s * 32);
      float aq = 0.f, ak = 0.f;
#pragma unroll
      for (int c = 0; c < 4; c++) {
        H8 hc = hrow[c];
#pragma unroll
        for (int j = 0; j < 4; j++) {
          aq = fdot2(hc.h[j], wq[c].h[j], aq);
          ak = fdot2(hc.h[j], wk[c].h[j], ak);
        }
      }
      float qss = red8(aq * aq);
      float kss = red8(ak * ak);
      float qv = aq * rsqrtf(qss * (1.0f / HD_) + 1e-6f) * qw;
      float kv = ak * rsqrtf(kss * (1.0f / HD_) + 1e-6f) * kw;
      if (TEMPORAL) {
        float ang = (float)s * theta;
        float c, sn;
        __sincosf(ang, &sn, &c);
        float qp = __shfl_xor(qv, 4);
        float kp = __shfl_xor(kv, 4);
        qv = (hd < 4) ? (qv * c - qp * sn) : (qv * c + qp * sn);
        kv = (hd < 4) ? (kv * c - kp * sn) : (kv * c + kp * sn);
      }
      qh[s * 32 + d] = (_Float16)(qv * qscale);  // exp2-ready
      kh[s * 32 + d] = (_Float16)kv;
    }
  }
  __syncthreads();

  // ---- phase 3a: stash this thread's q rows in regs ----
  const int g = tid;
  const bool act3 = (2 * g < 4 * S);
  const int qi = g >> 1;
  const int hp = g & 1;  // head pair
  H8 qa, qb;
  if (act3) {
    const _Float16* qp = qh + qi * 32 + hp * 16;
    qa.v = *(const h8*)qp;
    qb.v = *(const h8*)(qp + 8);
  }
  __syncthreads();

  // ---- phase 3b: v = h @ Wv -> qh (overwrites q; q is in regs now) ----
  {
    H8 wv[4];
    {
      const h8* wvp = (const h8*)(W16 + 2048 + e * 32);
#pragma unroll
      for (int j = 0; j < 4; j++) wv[j].v = wvp[j];
    }
    for (int idx = tid; idx < S * E_; idx += 256) {
      int s = idx >> 5;
      const H8* hrow = (const H8*)(hbuf + s * 32);
      float av = 0.f;
#pragma unroll
      for (int c = 0; c < 4; c++) {
        H8 hc = hrow[c];
#pragma unroll
        for (int j = 0; j < 4; j++) av = fdot2(hc.h[j], wv[c].h[j], av);
      }
      qh[s * 32 + e] = (_Float16)av;
    }
  }
  __syncthreads();

  // ---- phase 3c: attention, single-pass softmax (scores bounded) ----
  if (act3) {
    float l0 = 0.f, l1 = 0.f;
    h2 acc[8] = {};
    const _Float16* kp = kh + hp * 16;
    const _Float16* vp = qh + hp * 16;
#pragma unroll 4
    for (int k = 0; k < S; k++) {
      H8 ka, kb, va, vb;
      ka.v = *(const h8*)kp;
      kb.v = *(const h8*)(kp + 8);
      va.v = *(const h8*)vp;
      vb.v = *(const h8*)(vp + 8);
      kp += 32; vp += 32;
      float s0 = fdot2(qa.h[0], ka.h[0], fdot2(qa.h[1], ka.h[1],
                 fdot2(qa.h[2], ka.h[2], fdot2(qa.h[3], ka.h[3], 0.f))));
      float s1 = fdot2(qb.h[0], kb.h[0], fdot2(qb.h[1], kb.h[1],
                 fdot2(qb.h[2], kb.h[2], fdot2(qb.h[3], kb.h[3], 0.f))));
      float e0 = __builtin_amdgcn_exp2f(s0);
      float e1 = __builtin_amdgcn_exp2f(s1);
      l0 += e0; l1 += e1;
      h2 p0 = pkrtz(e0, e0);
      h2 p1 = pkrtz(e1, e1);
      acc[0] += p0 * va.h[0]; acc[1] += p0 * va.h[1];
      acc[2] += p0 * va.h[2]; acc[3] += p0 * va.h[3];
      acc[4] += p1 * vb.h[0]; acc[5] += p1 * vb.h[1];
      acc[6] += p1 * vb.h[2]; acc[7] += p1 * vb.h[3];
    }
    float iv0 = 1.0f / l0, iv1 = 1.0f / l1;
    h2 il0 = pkrtz(iv0, iv0), il1 = pkrtz(iv1, iv1);
    H8 o0, o1;
#pragma unroll
    for (int j = 0; j < 4; j++) {
      o0.h[j] = acc[j] * il0;
      o1.h[j] = acc[4 + j] * il1;
    }
    _Float16* op = hbuf + qi * 32 + hp * 16;  // h is dead; o overwrites
    *(h8*)op = o0.v;
    *(h8*)(op + 8) = o1.v;
  }
  __syncthreads();

  // ---- phase 4: ao = o@Wo, x += rms(ao); h2 = rms(x) -> hbuf ----
  {
    H8 wo[4];
    {
      const h8* wop = (const h8*)(W16 + 3072 + e * 32);
#pragma unroll
      for (int j = 0; j < 4; j++) wo[j].v = wop[j];
    }
#pragma unroll
    for (int k = 0; k < SREG; k++) {
      int s = srow + 8 * k;
      if (S % 8 == 0 || s < S) {
        const H8* orow = (const H8*)(hbuf + s * 32);
        float a = 0.f;
#pragma unroll
        for (int c = 0; c < 4; c++) {
          H8 oc = orow[c];
#pragma unroll
          for (int j = 0; j < 4; j++) a = fdot2(oc.h[j], wo[c].h[j], a);
        }
        float ss = red32(a * a);
        xr[k] += a * rsqrtf(ss * (1.0f / E_) + 1e-6f) * nw1;
        float hx = xr[k];
        float s2s = red32(hx * hx);
        // row s touched only by this half-wave; lockstep => write-after-read safe
        hbuf[s * 32 + e] = (_Float16)(hx * rsqrtf(s2s * (1.0f / E_) + 1e-6f) * nw2);
      }
    }
  }
  __syncthreads();

  // ---- phase 5: ffn = silu(h2@Wg) * (h2@Wvl) -> ffnb (fp16) ----
  {
    const int f = tid & 63;
    H8 wg[4], wl[4];
    {
      const h8* a8 = (const h8*)(W16 + 4096 + f * 32);
      const h8* b8 = (const h8*)(W16 + 6144 + f * 32);
#pragma unroll
      for (int j = 0; j < 4; j++) { wg[j].v = a8[j]; wl[j].v = b8[j]; }
    }
    for (int idx = tid; idx < S * FFN_; idx += 256) {
      int s = idx >> 6;
      const H8* hrow = (const H8*)(hbuf + s * 32);
      float gq = 0.f, vv = 0.f;
#pragma unroll
      for (int c = 0; c < 4; c++) {
        H8 hc = hrow[c];
#pragma unroll
        for (int j = 0; j < 4; j++) {
          gq = fdot2(hc.h[j], wg[c].h[j], gq);
          vv = fdot2(hc.h[j], wl[c].h[j], vv);
        }
      }
      float sg = gq / (1.0f + __expf(-gq));
      ffnb[s * FFN_ + f] = (_Float16)(sg * vv);
    }
  }
  __syncthreads();

  // ---- phase 6: out = ffn@Wout^T, x += rms(out), store ----
  {
    H8 wh[8];
    {
      const h8* whp = (const h8*)(W16 + 8192 + e * 64);
#pragma unroll
      for (int j = 0; j < 8; j++) wh[j].v = whp[j];
    }
#pragma unroll
    for (int k = 0; k < SREG; k++) {
      int s = srow + 8 * k;
      if (S % 8 == 0 || s < S) {
        const H8* frow = (const H8*)(ffnb + s * FFN_);
        float p0 = 0.f, p1 = 0.f, p2 = 0.f, p3 = 0.f;
#pragma unroll
        for (int c = 0; c < 8; c++) {
          H8 fc = frow[c];
          p0 = fdot2(fc.h[0], wh[c].h[0], p0);
          p1 = fdot2(fc.h[1], wh[c].h[1], p1);
          p2 = fdot2(fc.h[2], wh[c].h[2], p2);
          p3 = fdot2(fc.h[3], wh[c].h[3], p3);
        }
        float a = (p0 + p1) + (p2 + p3);
        float ss = red32(a * a);
        xr[k] += a * rsqrtf(ss * (1.0f / E_) + 1e-6f) * nw3;
        X[base + s * stride + e] = xr[k];
      }
    }
  }
}

// ---------------- final norm + output extraction ----------------
__global__ __launch_bounds__(256) void final_kernel(const float* __restrict__ X,
                                                    const float* __restrict__ fnw,
                                                    float* __restrict__ out) {
  int tok = blockIdx.x * 8 + (threadIdx.x >> 5);
  int e = threadIdx.x & 31;
  if (tok >= B_ * 3) return;
  int b = tok / 3, j = tok % 3;
  const float* xp = X + ((size_t)(b * T_ + (T_ - 1)) * SLOTS_ + OBS_ + j) * E_;
  float v = xp[e];
  float ss = red32(v * v);
  out[j * (B_ * E_) + b * E_ + e] = v * rsqrtf(ss * (1.0f / E_) + 1e-6f) * fnw[e];
}

extern "C" void kernel_launch(void* const* d_in, const int* in_sizes, int n_in,
                              void* d_out, int out_size, void* d_ws, size_t ws_size,
                              hipStream_t stream) {
  (void)in_sizes; (void)n_in; (void)out_size; (void)ws_size;
  const float* obs          = (const float*)d_in[0];
  const float* W_val        = (const float*)d_in[1];
  const float* b_val        = (const float*)d_in[2];
  const float* input_norm_w = (const float*)d_in[3];
  const float* dim_embed    = (const float*)d_in[4];
  const float* cls_tokens   = (const float*)d_in[5];
  const float* final_norm_w = (const float*)d_in[6];
  const float* s_n4   = (const float*)d_in[14];
  const float* s_qkn  = (const float*)d_in[15];
  const float* t_n4   = (const float*)d_in[23];
  const float* t_qkn  = (const float*)d_in[24];

  float* X = (float*)d_ws;  // B*T*SLOTS*E floats = 17.56 MB
  _Float16* W16 = (_Float16*)((char*)d_ws + X_BYTES);  // 5*10240 halves
  float* out = (float*)d_out;

  WPtrs wp;
  wp.sWq   = (const float*)d_in[7];
  wp.sWk   = (const float*)d_in[8];
  wp.sWv   = (const float*)d_in[9];
  wp.sWo   = (const float*)d_in[10];
  wp.sWg   = (const float*)d_in[11];
  wp.sWvl  = (const float*)d_in[12];
  wp.sWout = (const float*)d_in[13];
  wp.tWq   = (const float*)d_in[16];
  wp.tWk   = (const float*)d_in[17];
  wp.tWv   = (const float*)d_in[18];
  wp.tWo   = (const float*)d_in[19];
  wp.tWg   = (const float*)d_in[20];
  wp.tWvl  = (const float*)d_in[21];
  wp.tWout = (const float*)d_in[22];
  cvt_weights_kernel<<<100, 256, 0, stream>>>(wp, W16);

  const int total_tokens = B_ * T_ * SLOTS_;
  embed_kernel<<<(total_tokens + 7) / 8, 256, 0, stream>>>(
      obs, W_val, b_val, input_norm_w, dim_embed, cls_tokens, X);

  const int N4 = 4 * E_;   // 128
  const int QN = 2 * HD_;  // 16

#define SPATIAL(i)                                                     \
  attn_block_kernel<SLOTS_, false><<<B_ * T_, 256, 0, stream>>>(       \
      X, W16 + (i)*WBLK, s_n4 + (i)*N4, s_qkn + (i)*QN)
#define TEMPORAL(i)                                                    \
  attn_block_kernel<T_, true><<<B_ * SLOTS_, 256, 0, stream>>>(        \
      X, W16 + (3 + (i)) * WBLK, t_n4 + (i)*N4, t_qkn + (i)*QN)

  SPATIAL(0);
  TEMPORAL(0);
  SPATIAL(1);
  TEMPORAL(1);
  SPATIAL(2);

#undef SPATIAL
#undef TEMPORAL

  final_kernel<<<6, 256, 0, stream>>>(X, final_norm_w, out);
}